// Round 5
// baseline (735.907 us; speedup 1.0000x reference)
//
#include <hip/hip_runtime.h>
#include <hip/hip_bf16.h>
#include <math.h>

// Problem constants (match reference)
#define B_   16
#define T_   1024
#define D_   512
#define V_   5000
#define VP_  5120         // V padded to 128
#define L_   128
#define S_   257          // 2L+1 extended states
#define J_   129          // blank + L label slots
#define M_   (B_*T_)      // 16384 rows of the projection
#define NT_  40           // ceil(V/128) N-tiles for partial LSE
#define NEGF (-1e30f)

// hardware base-2 transcendentals (v_exp_f32 / v_log_f32)
#define EXP2F(x) __builtin_amdgcn_exp2f(x)
#define LOG2F(x) __builtin_amdgcn_logf(x)

typedef __attribute__((ext_vector_type(8))) short short8;
typedef __attribute__((ext_vector_type(4))) float float4v;

__device__ inline void load_lds_16(const void* g, void* l) {
    __builtin_amdgcn_global_load_lds(
        (const __attribute__((address_space(1))) unsigned int*)g,
        (__attribute__((address_space(3))) unsigned int*)l, 16, 0, 0);
}

__device__ inline unsigned short f2bf(float f) {
    union { float f; unsigned int u; } x; x.f = f;
    // RNE round to bf16
    unsigned int r = x.u + 0x7FFFu + ((x.u >> 16) & 1u);
    return (unsigned short)(r >> 16);
}

// ---------------------------------------------------------------------------
// Kernel 0a: hs fp32 -> bf16 row-major (M, 512)
// ---------------------------------------------------------------------------
__global__ __launch_bounds__(256) void k_convert_hs(
    const float* __restrict__ hs, unsigned short* __restrict__ Ah)
{
    size_t base = ((size_t)blockIdx.x * 256 + threadIdx.x) * 8;
    float4 a = *(const float4*)&hs[base];
    float4 b = *(const float4*)&hs[base + 4];
    short8 o;
    o[0] = (short)f2bf(a.x); o[1] = (short)f2bf(a.y);
    o[2] = (short)f2bf(a.z); o[3] = (short)f2bf(a.w);
    o[4] = (short)f2bf(b.x); o[5] = (short)f2bf(b.y);
    o[6] = (short)f2bf(b.z); o[7] = (short)f2bf(b.w);
    *(short8*)&Ah[base] = o;
}

// ---------------------------------------------------------------------------
// Kernel 0b: W (512, 5000) fp32 -> Wt (5120, 512) bf16 transposed, pad zero
// ---------------------------------------------------------------------------
__global__ __launch_bounds__(256) void k_transpose_w(
    const float* __restrict__ W, unsigned short* __restrict__ Wt)
{
    __shared__ float tile[32][33];
    int v0 = blockIdx.x * 32, k0 = blockIdx.y * 32;
    int tx = threadIdx.x, ty = threadIdx.y;  // (32, 8)
#pragma unroll
    for (int r = 0; r < 4; r++) {
        int kk = r * 8 + ty;
        float val = 0.f;
        if (v0 + tx < V_) val = W[(size_t)(k0 + kk) * V_ + v0 + tx];
        tile[kk][tx] = val;
    }
    __syncthreads();
#pragma unroll
    for (int r = 0; r < 4; r++) {
        int vloc = r * 8 + ty;
        Wt[(size_t)(v0 + vloc) * D_ + k0 + tx] = f2bf(tile[tx][vloc]);
    }
}

// ---------------------------------------------------------------------------
// Kernel 1: C = hs@W + b with fused per-row partial logsumexp per 128-col
// tile. bf16 MFMA 16x16x32, 128x128 block tile, 4 waves (2x2), 4x4 frags,
// global_load_lds width-16 staging. Writes (max, sumexp) partials only.
// ---------------------------------------------------------------------------
__global__ __launch_bounds__(256) void k_gemm_lse_mfma(
    const unsigned short* __restrict__ Ah,   // (M, 512) bf16
    const unsigned short* __restrict__ Wt,   // (5120, 512) bf16 = W^T
    const float* __restrict__ bias,          // (5000)
    float* __restrict__ part_m,              // (M, NT_)
    float* __restrict__ part_s)              // (M, NT_)
{
    __shared__ unsigned short As[128 * 32];  // [m][k] k-contiguous
    __shared__ unsigned short Bs[128 * 32];  // [n][k]
    __shared__ float sm_m[2][128];
    __shared__ float sm_s[2][128];

    const int bx = blockIdx.x;          // row tile (128)
    const int by = blockIdx.y;          // col tile (40)
    const int tid = threadIdx.x;
    const int rowBase = bx * 128, colBase = by * 128;
    const int lane = tid & 63, wv = tid >> 6;
    const int wi = wv >> 1, wj = wv & 1;    // 2x2 wave grid
    const int g = lane >> 4, lo = lane & 15;

    float4v acc[4][4];
#pragma unroll
    for (int i = 0; i < 4; i++)
#pragma unroll
        for (int j = 0; j < 4; j++) acc[i][j] = (float4v){0.f, 0.f, 0.f, 0.f};

    for (int it = 0; it < 16; it++) {
        const int k0 = it * 32;
        __syncthreads();
        // stage A: 128 rows x 32 bf16 = 8192 B; 512 slots of 16 B, 2/thread
#pragma unroll
        for (int l = 0; l < 2; l++) {
            int slot = tid + l * 256;
            int r = slot >> 2, q = slot & 3;
            load_lds_16(&Ah[(size_t)(rowBase + r) * D_ + k0 + q * 8],
                        &As[r * 32 + q * 8]);
            load_lds_16(&Wt[(size_t)(colBase + r) * D_ + k0 + q * 8],
                        &Bs[r * 32 + q * 8]);
        }
        __syncthreads();

        short8 a[4], b[4];
#pragma unroll
        for (int i = 0; i < 4; i++)
            a[i] = *(const short8*)&As[(wi * 64 + i * 16 + lo) * 32 + g * 8];
#pragma unroll
        for (int j = 0; j < 4; j++)
            b[j] = *(const short8*)&Bs[(wj * 64 + j * 16 + lo) * 32 + g * 8];
#pragma unroll
        for (int i = 0; i < 4; i++)
#pragma unroll
            for (int j = 0; j < 4; j++)
                acc[i][j] = __builtin_amdgcn_mfma_f32_16x16x32_bf16(
                    a[i], b[j], acc[i][j], 0, 0, 0);
    }

    // Epilogue: per-row max / sumexp over this wave's 64 cols, then combine
    // the two wj waves in LDS. D-frag mapping: col = lane&15, row=(lane>>4)*4+reg.
    float bj[4]; bool vj[4];
#pragma unroll
    for (int j = 0; j < 4; j++) {
        int col = colBase + wj * 64 + j * 16 + lo;
        vj[j] = (col < V_);
        bj[j] = vj[j] ? bias[col] : 0.f;
    }
#pragma unroll
    for (int i = 0; i < 4; i++) {
#pragma unroll
        for (int r = 0; r < 4; r++) {
            float m = -INFINITY;
#pragma unroll
            for (int j = 0; j < 4; j++)
                if (vj[j]) m = fmaxf(m, acc[i][j][r] + bj[j]);
#pragma unroll
            for (int off = 1; off < 16; off <<= 1)
                m = fmaxf(m, __shfl_xor(m, off, 16));
            float s = 0.f;
#pragma unroll
            for (int j = 0; j < 4; j++)
                if (vj[j]) s += __expf(acc[i][j][r] + bj[j] - m);
#pragma unroll
            for (int off = 1; off < 16; off <<= 1)
                s += __shfl_xor(s, off, 16);
            if (lo == 0) {
                int rowl = wi * 64 + i * 16 + g * 4 + r;
                sm_m[wj][rowl] = m;
                sm_s[wj][rowl] = s;
            }
        }
    }
    __syncthreads();
    if (tid < 128) {
        float m0 = sm_m[0][tid], m1 = sm_m[1][tid];
        float m = fmaxf(m0, m1);
        float s = 0.f;
        if (m > -INFINITY) {
            s = sm_s[0][tid] * __expf(m0 - m) + sm_s[1][tid] * __expf(m1 - m);
        }
        part_m[(size_t)(rowBase + tid) * NT_ + by] = m;
        part_s[(size_t)(rowBase + tid) * NT_ + by] = s;
    }
}

// ---------------------------------------------------------------------------
// Kernel 2: combine LSE partials -> lse[row]
// ---------------------------------------------------------------------------
__global__ void k_lse_reduce(const float* __restrict__ part_m,
                             const float* __restrict__ part_s,
                             float* __restrict__ lse)
{
    int row = blockIdx.x * 256 + threadIdx.x;
    if (row >= M_) return;
    float m = -INFINITY;
    for (int i = 0; i < NT_; i++) m = fmaxf(m, part_m[(size_t)row * NT_ + i]);
    float s = 0.f;
    for (int i = 0; i < NT_; i++)
        s += part_s[(size_t)row * NT_ + i] * __expf(part_m[(size_t)row * NT_ + i] - m);
    lse[row] = m + __logf(s);
}

// ---------------------------------------------------------------------------
// Kernel 3: gather needed W columns (blank + per-batch labels) transposed to
// row-major Wg[b][j][d] so the dot kernel reads contiguously. Also bias.
// ---------------------------------------------------------------------------
__global__ void k_gather_w(const float* __restrict__ W,
                           const float* __restrict__ bias,
                           const int* __restrict__ ys,
                           float* __restrict__ Wg,     // (B, J, 512)
                           float* __restrict__ bg)     // (B, J)
{
    int b = blockIdx.x, j = blockIdx.y;
    int lab = (j == 0) ? 0 : ys[b * L_ + (j - 1)];
    float* dst = &Wg[((size_t)b * J_ + j) * D_];
    for (int d = threadIdx.x; d < D_; d += blockDim.x)
        dst[d] = W[(size_t)d * V_ + lab];
    if (threadIdx.x == 0) bg[b * J_ + j] = bias[lab];
}

// ---------------------------------------------------------------------------
// Kernel 4: label logits ll[b][t][j] = dot(hs[b,t,:], Wg[b,j,:]) + bg[b,j]
// ---------------------------------------------------------------------------
#define HPAD 516
__global__ __launch_bounds__(256) void k_label_logits(
    const float* __restrict__ hs,
    const float* __restrict__ Wg,
    const float* __restrict__ bg,
    float* __restrict__ ll)        // (B, T, J)
{
    __shared__ float hs_s[16 * HPAD];
    int b = blockIdx.x, tBase = blockIdx.y * 16;
    int tid = threadIdx.x;
#pragma unroll
    for (int l = 0; l < 8; l++) {
        int f = tid + l * 256;
        int t = f >> 7, q = f & 127;
        float4 h4 = *(const float4*)&hs[((size_t)(b * T_) + tBase + t) * D_ + q * 4];
        *(float4*)&hs_s[t * HPAD + q * 4] = h4;
    }
    __syncthreads();
    for (int base = 0; base < 16 * J_; base += 256) {
        int idx = base + tid;
        if (idx < 16 * J_) {
            int t = idx & 15, j = idx >> 4;
            const float* w = &Wg[((size_t)b * J_ + j) * D_];
            const float* h = &hs_s[t * HPAD];
            float acc = 0.f;
            for (int d = 0; d < D_; d += 4) {
                float4 w4 = *(const float4*)&w[d];
                float4 h4 = *(const float4*)&h[d];
                acc = fmaf(w4.x, h4.x, acc); acc = fmaf(w4.y, h4.y, acc);
                acc = fmaf(w4.z, h4.z, acc); acc = fmaf(w4.w, h4.w, acc);
            }
            ll[((size_t)(b * T_) + tBase + t) * J_ + j] = acc + bg[b * J_ + j];
        }
    }
}

// ---------------------------------------------------------------------------
// Kernel 5: CTC alpha recursion — ONE WAVE per batch, 5 states per lane,
// wave-synchronous, log2-domain lse3, and DEPTH-8 software-pipelined loads
// (register circular buffer, statically unrolled slots) so the ~600-900 cyc
// cross-XCD load latency is hidden across 8 steps.
// ---------------------------------------------------------------------------
#define LOG2E 1.4426950408889634f
#define LN2   0.6931471805599453f
#define PD_   8            // prefetch depth

__global__ __launch_bounds__(64) void k_ctc_alpha(
    const float* __restrict__ ll,      // (B, T, J)
    const float* __restrict__ lse,     // (B*T)
    const int* __restrict__ hlens,
    const int* __restrict__ ys,
    const int* __restrict__ ys_lens,
    float* __restrict__ loss_b)        // (B)
{
    __shared__ float fin[320];
    const int b = blockIdx.x;
    const int lane = threadIdx.x;
    const int hl = hlens[b];
    const int sbase = lane * 5;
    const float* __restrict__ llb  = ll  + (size_t)b * T_ * J_;
    const float* __restrict__ lseb = lse + (size_t)b * T_;

    // Per-state constants: validity, label slot j, skip-allowed flag
    bool  val[5]; int jr[5]; bool al3[5];
#pragma unroll
    for (int r = 0; r < 5; r++) {
        int s = sbase + r;
        val[r] = (s < S_);
        jr[r] = 0; al3[r] = false;
        if (val[r] && (s & 1)) {
            jr[r] = (s + 1) >> 1;
            if (s >= 3)
                al3[r] = (ys[b * L_ + ((s - 1) >> 1)] != ys[b * L_ + ((s - 3) >> 1)]);
        }
    }

    // t = 0 init (log2 units)
    float a[5];
    {
        float lse0 = lseb[0];
#pragma unroll
        for (int r = 0; r < 5; r++) {
            int s = sbase + r;
            float v = NEGF;
            if (s == 0) v = (llb[0] - lse0) * LOG2E;
            if (s == 1) v = (llb[1] - lse0) * LOG2E;
            a[r] = v;
        }
    }

    // Prefetch pipeline: slot p holds loads for time t = (current block) + p.
    float lpn[PD_][5], lsen[PD_];
#pragma unroll
    for (int p = 0; p < PD_; p++) {
        int t = 1 + p;
        if (t < hl) {
            lsen[p] = lseb[t];
            size_t rowoff = (size_t)t * J_;
#pragma unroll
            for (int r = 0; r < 5; r++) lpn[p][r] = llb[rowoff + jr[r]];
        }
    }

    int tb = 1;
    for (; tb + PD_ <= hl; tb += PD_) {
#pragma unroll
        for (int p = 0; p < PD_; p++) {
            const int t = tb + p;
            // consume slot p (convert to log2 units off the chain)
            float lp[5];
#pragma unroll
            for (int r = 0; r < 5; r++) lp[r] = (lpn[p][r] - lsen[p]) * LOG2E;
            // refill slot p for t + PD_ (stays in flight for 8 steps)
            if (t + PD_ < hl) {
                lsen[p] = lseb[t + PD_];
                size_t rowoff = (size_t)(t + PD_) * J_;
#pragma unroll
                for (int r = 0; r < 5; r++) lpn[p][r] = llb[rowoff + jr[r]];
            }
            // recurrence
            float p4 = __shfl_up(a[4], 1);   // s-1 for r=0
            float p3 = __shfl_up(a[3], 1);   // s-2 for r=0
            float na[5];
#pragma unroll
            for (int r = 0; r < 5; r++) {
                float a1 = a[r];
                float a2, a3;
                if (r == 0)      { a2 = p4;      a3 = p3; }
                else if (r == 1) { a2 = a[0];    a3 = p4; }
                else             { a2 = a[r-1];  a3 = a[r-2]; }
                if (r == 0 && lane == 0) { a2 = NEGF; a3 = NEGF; }
                a3 = al3[r] ? a3 : NEGF;
                float m = fmaxf(fmaxf(a1, a2), a3);
                float v = m + LOG2F(EXP2F(a1 - m) + EXP2F(a2 - m) + EXP2F(a3 - m));
                na[r] = val[r] ? (v + lp[r]) : NEGF;
            }
#pragma unroll
            for (int r = 0; r < 5; r++) a[r] = na[r];
        }
    }
    // epilogue: remaining t in [tb, hl), slots already loaded
#pragma unroll
    for (int p = 0; p < PD_; p++) {
        const int t = tb + p;
        if (t < hl) {
            float lp[5];
#pragma unroll
            for (int r = 0; r < 5; r++) lp[r] = (lpn[p][r] - lsen[p]) * LOG2E;
            float p4 = __shfl_up(a[4], 1);
            float p3 = __shfl_up(a[3], 1);
            float na[5];
#pragma unroll
            for (int r = 0; r < 5; r++) {
                float a1 = a[r];
                float a2, a3;
                if (r == 0)      { a2 = p4;      a3 = p3; }
                else if (r == 1) { a2 = a[0];    a3 = p4; }
                else             { a2 = a[r-1];  a3 = a[r-2]; }
                if (r == 0 && lane == 0) { a2 = NEGF; a3 = NEGF; }
                a3 = al3[r] ? a3 : NEGF;
                float m = fmaxf(fmaxf(a1, a2), a3);
                float v = m + LOG2F(EXP2F(a1 - m) + EXP2F(a2 - m) + EXP2F(a3 - m));
                na[r] = val[r] ? (v + lp[r]) : NEGF;
            }
#pragma unroll
            for (int r = 0; r < 5; r++) a[r] = na[r];
        }
    }

    // readout
#pragma unroll
    for (int r = 0; r < 5; r++) fin[sbase + r] = a[r];
    __syncthreads();
    if (lane == 0) {
        int yl = ys_lens[b];
        int i1 = 2 * yl;
        int i2 = (i1 > 0) ? i1 - 1 : 0;
        float x = fin[i1], y = fin[i2];
        float m = fmaxf(x, y);
        float llv = (m + LOG2F(EXP2F(x - m) + EXP2F(y - m))) * LN2;
        float loss = -llv;
        if (!isfinite(loss) || loss >= 1e29f) loss = 0.f;
        loss_b[b] = loss;
    }
}

// ---------------------------------------------------------------------------
// Kernel 6: final scalar: sum(loss_b) / sum(ys_lens)
// ---------------------------------------------------------------------------
__global__ void k_final(const float* __restrict__ loss_b,
                        const int* __restrict__ ys_lens,
                        float* __restrict__ out)
{
    int t = threadIdx.x;
    float v = (t < B_) ? loss_b[t] : 0.f;
    int   n = (t < B_) ? ys_lens[t] : 0;
    for (int off = 32; off > 0; off >>= 1) {
        v += __shfl_down(v, off, 64);
        n += __shfl_down(n, off, 64);
    }
    if (t == 0) out[0] = v / (float)n;
}

// ---------------------------------------------------------------------------
extern "C" void kernel_launch(void* const* d_in, const int* in_sizes, int n_in,
                              void* d_out, int out_size, void* d_ws, size_t ws_size,
                              hipStream_t stream)
{
    const float* hs      = (const float*)d_in[0];  // (B,T,D)
    const int*   hlens   = (const int*)  d_in[1];  // (B)
    const int*   ys      = (const int*)  d_in[2];  // (B,L)
    const int*   ys_lens = (const int*)  d_in[3];  // (B)
    const float* W       = (const float*)d_in[4];  // (D,V)
    const float* bias    = (const float*)d_in[5];  // (V)
    float* out = (float*)d_out;

    // Workspace layout (floats; all offsets 16B-aligned). Total ~40 MB.
    float* ws = (float*)d_ws;
    float* part_m = ws;                               // M*NT   = 655360
    float* part_s = part_m + (size_t)M_ * NT_;        // 655360
    float* lse    = part_s + (size_t)M_ * NT_;        // 16384
    float* Wg     = lse    + M_;                      // B*J*D  = 1056768
    float* bg     = Wg     + (size_t)B_ * J_ * D_;    // 2064
    float* llab   = bg     + (size_t)B_ * J_;         // 2113536
    float* loss_b = llab   + (size_t)B_ * T_ * J_;    // 16
    unsigned short* Ah = (unsigned short*)(loss_b + 16);   // M*D bf16 = 16.8MB
    unsigned short* Wt = Ah + (size_t)M_ * D_;             // VP*D bf16 = 5.2MB

    // 0) convert hs -> bf16; W -> bf16 transposed (N-major, padded to 5120)
    k_convert_hs<<<(M_ * D_) / (256 * 8), 256, 0, stream>>>(hs, Ah);
    k_transpose_w<<<dim3(VP_ / 32, D_ / 32), dim3(32, 8), 0, stream>>>(W, Wt);
    // 1) projection + fused partial LSE (the 84-GFLOP bulk) via bf16 MFMA
    k_gemm_lse_mfma<<<dim3(M_ / 128, NT_), 256, 0, stream>>>(Ah, Wt, bias, part_m, part_s);
    // 2) gather label columns of W
    k_gather_w<<<dim3(B_, J_), 128, 0, stream>>>(W, bias, ys, Wg, bg);
    // 3) label logits
    k_label_logits<<<dim3(B_, T_ / 16), 256, 0, stream>>>(hs, Wg, bg, llab);
    // 4) combine LSE partials
    k_lse_reduce<<<M_ / 256, 256, 0, stream>>>(part_m, part_s, lse);
    // 5) CTC forward recursion — one wave per batch, depth-8 pipelined loads
    k_ctc_alpha<<<B_, 64, 0, stream>>>(llab, lse, hlens, ys, ys_lens, loss_b);
    // 6) final scalar
    k_final<<<1, 64, 0, stream>>>(loss_b, ys_lens, out);
}

// Round 6
// 717.111 us; speedup vs baseline: 1.0262x; 1.0262x over previous
//
#include <hip/hip_runtime.h>
#include <hip/hip_bf16.h>
#include <math.h>

// Problem constants (match reference)
#define B_   16
#define T_   1024
#define D_   512
#define V_   5000
#define VP_  5120         // V padded to 128
#define L_   128
#define S_   257          // 2L+1 extended states
#define J_   129          // blank + L label slots
#define M_   (B_*T_)      // 16384 rows of the projection
#define NT_  40           // ceil(V/128) N-tiles for partial LSE
#define NEGF (-1e30f)

// hardware base-2 transcendentals (v_exp_f32 / v_log_f32)
#define EXP2F(x) __builtin_amdgcn_exp2f(x)
#define LOG2F(x) __builtin_amdgcn_logf(x)

typedef __attribute__((ext_vector_type(8))) short short8;
typedef __attribute__((ext_vector_type(4))) float float4v;

__device__ inline void load_lds_16(const void* g, void* l) {
    __builtin_amdgcn_global_load_lds(
        (const __attribute__((address_space(1))) unsigned int*)g,
        (__attribute__((address_space(3))) unsigned int*)l, 16, 0, 0);
}

__device__ inline unsigned short f2bf(float f) {
    union { float f; unsigned int u; } x; x.f = f;
    // RNE round to bf16
    unsigned int r = x.u + 0x7FFFu + ((x.u >> 16) & 1u);
    return (unsigned short)(r >> 16);
}

// ---------------------------------------------------------------------------
// Kernel 0a: hs fp32 -> bf16 row-major (M, 512)
// ---------------------------------------------------------------------------
__global__ __launch_bounds__(256) void k_convert_hs(
    const float* __restrict__ hs, unsigned short* __restrict__ Ah)
{
    size_t base = ((size_t)blockIdx.x * 256 + threadIdx.x) * 8;
    float4 a = *(const float4*)&hs[base];
    float4 b = *(const float4*)&hs[base + 4];
    short8 o;
    o[0] = (short)f2bf(a.x); o[1] = (short)f2bf(a.y);
    o[2] = (short)f2bf(a.z); o[3] = (short)f2bf(a.w);
    o[4] = (short)f2bf(b.x); o[5] = (short)f2bf(b.y);
    o[6] = (short)f2bf(b.z); o[7] = (short)f2bf(b.w);
    *(short8*)&Ah[base] = o;
}

// ---------------------------------------------------------------------------
// Kernel 0b: W (512, 5000) fp32 -> Wt (5120, 512) bf16 transposed, pad zero
// ---------------------------------------------------------------------------
__global__ __launch_bounds__(256) void k_transpose_w(
    const float* __restrict__ W, unsigned short* __restrict__ Wt)
{
    __shared__ float tile[32][33];
    int v0 = blockIdx.x * 32, k0 = blockIdx.y * 32;
    int tx = threadIdx.x, ty = threadIdx.y;  // (32, 8)
#pragma unroll
    for (int r = 0; r < 4; r++) {
        int kk = r * 8 + ty;
        float val = 0.f;
        if (v0 + tx < V_) val = W[(size_t)(k0 + kk) * V_ + v0 + tx];
        tile[kk][tx] = val;
    }
    __syncthreads();
#pragma unroll
    for (int r = 0; r < 4; r++) {
        int vloc = r * 8 + ty;
        Wt[(size_t)(v0 + vloc) * D_ + k0 + tx] = f2bf(tile[tx][vloc]);
    }
}

// ---------------------------------------------------------------------------
// Kernel 1: C = hs@W + b with fused per-row partial logsumexp per 128-col
// tile. bf16 MFMA 16x16x32, 128x128 block tile, 4 waves (2x2), 4x4 frags,
// global_load_lds width-16 staging. Writes (max, sumexp) partials only.
// ---------------------------------------------------------------------------
__global__ __launch_bounds__(256) void k_gemm_lse_mfma(
    const unsigned short* __restrict__ Ah,   // (M, 512) bf16
    const unsigned short* __restrict__ Wt,   // (5120, 512) bf16 = W^T
    const float* __restrict__ bias,          // (5000)
    float* __restrict__ part_m,              // (M, NT_)
    float* __restrict__ part_s)              // (M, NT_)
{
    __shared__ unsigned short As[128 * 32];  // [m][k] k-contiguous
    __shared__ unsigned short Bs[128 * 32];  // [n][k]
    __shared__ float sm_m[2][128];
    __shared__ float sm_s[2][128];

    const int bx = blockIdx.x;          // row tile (128)
    const int by = blockIdx.y;          // col tile (40)
    const int tid = threadIdx.x;
    const int rowBase = bx * 128, colBase = by * 128;
    const int lane = tid & 63, wv = tid >> 6;
    const int wi = wv >> 1, wj = wv & 1;    // 2x2 wave grid
    const int g = lane >> 4, lo = lane & 15;

    float4v acc[4][4];
#pragma unroll
    for (int i = 0; i < 4; i++)
#pragma unroll
        for (int j = 0; j < 4; j++) acc[i][j] = (float4v){0.f, 0.f, 0.f, 0.f};

    for (int it = 0; it < 16; it++) {
        const int k0 = it * 32;
        __syncthreads();
        // stage A: 128 rows x 32 bf16 = 8192 B; 512 slots of 16 B, 2/thread
#pragma unroll
        for (int l = 0; l < 2; l++) {
            int slot = tid + l * 256;
            int r = slot >> 2, q = slot & 3;
            load_lds_16(&Ah[(size_t)(rowBase + r) * D_ + k0 + q * 8],
                        &As[r * 32 + q * 8]);
            load_lds_16(&Wt[(size_t)(colBase + r) * D_ + k0 + q * 8],
                        &Bs[r * 32 + q * 8]);
        }
        __syncthreads();

        short8 a[4], b[4];
#pragma unroll
        for (int i = 0; i < 4; i++)
            a[i] = *(const short8*)&As[(wi * 64 + i * 16 + lo) * 32 + g * 8];
#pragma unroll
        for (int j = 0; j < 4; j++)
            b[j] = *(const short8*)&Bs[(wj * 64 + j * 16 + lo) * 32 + g * 8];
#pragma unroll
        for (int i = 0; i < 4; i++)
#pragma unroll
            for (int j = 0; j < 4; j++)
                acc[i][j] = __builtin_amdgcn_mfma_f32_16x16x32_bf16(
                    a[i], b[j], acc[i][j], 0, 0, 0);
    }

    // Epilogue: per-row max / sumexp over this wave's 64 cols, then combine
    // the two wj waves in LDS. D-frag mapping: col = lane&15, row=(lane>>4)*4+reg.
    float bj[4]; bool vj[4];
#pragma unroll
    for (int j = 0; j < 4; j++) {
        int col = colBase + wj * 64 + j * 16 + lo;
        vj[j] = (col < V_);
        bj[j] = vj[j] ? bias[col] : 0.f;
    }
#pragma unroll
    for (int i = 0; i < 4; i++) {
#pragma unroll
        for (int r = 0; r < 4; r++) {
            float m = -INFINITY;
#pragma unroll
            for (int j = 0; j < 4; j++)
                if (vj[j]) m = fmaxf(m, acc[i][j][r] + bj[j]);
#pragma unroll
            for (int off = 1; off < 16; off <<= 1)
                m = fmaxf(m, __shfl_xor(m, off, 16));
            float s = 0.f;
#pragma unroll
            for (int j = 0; j < 4; j++)
                if (vj[j]) s += __expf(acc[i][j][r] + bj[j] - m);
#pragma unroll
            for (int off = 1; off < 16; off <<= 1)
                s += __shfl_xor(s, off, 16);
            if (lo == 0) {
                int rowl = wi * 64 + i * 16 + g * 4 + r;
                sm_m[wj][rowl] = m;
                sm_s[wj][rowl] = s;
            }
        }
    }
    __syncthreads();
    if (tid < 128) {
        float m0 = sm_m[0][tid], m1 = sm_m[1][tid];
        float m = fmaxf(m0, m1);
        float s = 0.f;
        if (m > -INFINITY) {
            s = sm_s[0][tid] * __expf(m0 - m) + sm_s[1][tid] * __expf(m1 - m);
        }
        part_m[(size_t)(rowBase + tid) * NT_ + by] = m;
        part_s[(size_t)(rowBase + tid) * NT_ + by] = s;
    }
}

// ---------------------------------------------------------------------------
// Kernel 2: combine LSE partials -> lse[row]
// ---------------------------------------------------------------------------
__global__ void k_lse_reduce(const float* __restrict__ part_m,
                             const float* __restrict__ part_s,
                             float* __restrict__ lse)
{
    int row = blockIdx.x * 256 + threadIdx.x;
    if (row >= M_) return;
    float m = -INFINITY;
    for (int i = 0; i < NT_; i++) m = fmaxf(m, part_m[(size_t)row * NT_ + i]);
    float s = 0.f;
    for (int i = 0; i < NT_; i++)
        s += part_s[(size_t)row * NT_ + i] * __expf(part_m[(size_t)row * NT_ + i] - m);
    lse[row] = m + __logf(s);
}

// ---------------------------------------------------------------------------
// Kernel 3: gather needed W columns (blank + per-batch labels) transposed to
// row-major Wg[b][j][d] so the dot kernel reads contiguously. Also bias.
// ---------------------------------------------------------------------------
__global__ void k_gather_w(const float* __restrict__ W,
                           const float* __restrict__ bias,
                           const int* __restrict__ ys,
                           float* __restrict__ Wg,     // (B, J, 512)
                           float* __restrict__ bg)     // (B, J)
{
    int b = blockIdx.x, j = blockIdx.y;
    int lab = (j == 0) ? 0 : ys[b * L_ + (j - 1)];
    float* dst = &Wg[((size_t)b * J_ + j) * D_];
    for (int d = threadIdx.x; d < D_; d += blockDim.x)
        dst[d] = W[(size_t)d * V_ + lab];
    if (threadIdx.x == 0) bg[b * J_ + j] = bias[lab];
}

// ---------------------------------------------------------------------------
// Kernel 4: label logits ll[b][t][j] = dot(hs[b,t,:], Wg[b,j,:]) + bg[b,j]
// ---------------------------------------------------------------------------
#define HPAD 516
__global__ __launch_bounds__(256) void k_label_logits(
    const float* __restrict__ hs,
    const float* __restrict__ Wg,
    const float* __restrict__ bg,
    float* __restrict__ ll)        // (B, T, J)
{
    __shared__ float hs_s[16 * HPAD];
    int b = blockIdx.x, tBase = blockIdx.y * 16;
    int tid = threadIdx.x;
#pragma unroll
    for (int l = 0; l < 8; l++) {
        int f = tid + l * 256;
        int t = f >> 7, q = f & 127;
        float4 h4 = *(const float4*)&hs[((size_t)(b * T_) + tBase + t) * D_ + q * 4];
        *(float4*)&hs_s[t * HPAD + q * 4] = h4;
    }
    __syncthreads();
    for (int base = 0; base < 16 * J_; base += 256) {
        int idx = base + tid;
        if (idx < 16 * J_) {
            int t = idx & 15, j = idx >> 4;
            const float* w = &Wg[((size_t)b * J_ + j) * D_];
            const float* h = &hs_s[t * HPAD];
            float acc = 0.f;
            for (int d = 0; d < D_; d += 4) {
                float4 w4 = *(const float4*)&w[d];
                float4 h4 = *(const float4*)&h[d];
                acc = fmaf(w4.x, h4.x, acc); acc = fmaf(w4.y, h4.y, acc);
                acc = fmaf(w4.z, h4.z, acc); acc = fmaf(w4.w, h4.w, acc);
            }
            ll[((size_t)(b * T_) + tBase + t) * J_ + j] = acc + bg[b * J_ + j];
        }
    }
}

// ---------------------------------------------------------------------------
// Kernel 5: CTC alpha recursion — one wave per batch, 5 states/lane, and
// BULK LDS staging of ll via global_load_lds: 48-row chunks (25 x 1024 B DMA)
// double-buffered, so per-step reads are LDS-local; chunk c+1's DMA is in
// flight while chunk c is consumed. lse[b][:] (4 KB) staged once up-front.
// Chunk global base t0*516-4 is 16B-aligned since t0 = 1 mod 4; the -4
// misalign shows up as +1 float in LDS offsets.
// ---------------------------------------------------------------------------
#define LOG2E 1.4426950408889634f
#define LN2   0.6931471805599453f
#define CH_   48           // rows per chunk
#define NLD_  25           // 16B x 64-lane DMA instructions per chunk (25600 B)

__global__ __launch_bounds__(64) void k_ctc_alpha(
    const float* __restrict__ ll,      // (B, T, J)
    const float* __restrict__ lse,     // (B*T)
    const int* __restrict__ hlens,
    const int* __restrict__ ys,
    const int* __restrict__ ys_lens,
    float* __restrict__ loss_b)        // (B)
{
    __shared__ float lseL[1024];
    __shared__ float chunkbuf[2][6400];   // 25600 B each
    __shared__ float fin[320];

    const int b = blockIdx.x;
    const int lane = threadIdx.x;
    const int hl = hlens[b];
    const int sbase = lane * 5;
    const float* __restrict__ llb  = ll  + (size_t)b * T_ * J_;
    const float* __restrict__ lseb = lse + (size_t)b * T_;
    const char*  llbase = (const char*)llb;

    // Per-state constants
    bool  val[5]; int jr[5]; bool al3[5];
#pragma unroll
    for (int r = 0; r < 5; r++) {
        int s = sbase + r;
        val[r] = (s < S_);
        jr[r] = 0; al3[r] = false;
        if (val[r] && (s & 1)) {
            jr[r] = (s + 1) >> 1;
            if (s >= 3)
                al3[r] = (ys[b * L_ + ((s - 1) >> 1)] != ys[b * L_ + ((s - 3) >> 1)]);
        }
    }

    // stage lse[b][0..1023] (4 KB) into LDS
#pragma unroll
    for (int i = 0; i < 4; i++)
        load_lds_16((const char*)lseb + i * 1024 + lane * 16,
                    (char*)lseL + i * 1024 + lane * 16);
    // stage chunk 0 (t0 = 1)
#pragma unroll
    for (int i = 0; i < NLD_; i++)
        load_lds_16(llbase + 512 + i * 1024 + lane * 16,            // 1*516-4
                    (char*)&chunkbuf[0][0] + i * 1024 + lane * 16);

    // t = 0 init (log2 units) — direct global scalar reads
    float a[5];
    {
        float lse0 = lseb[0];
#pragma unroll
        for (int r = 0; r < 5; r++) {
            int s = sbase + r;
            float v = NEGF;
            if (s == 0) v = (llb[0] - lse0) * LOG2E;
            if (s == 1) v = (llb[1] - lse0) * LOG2E;
            a[r] = v;
        }
    }

    int bsel = 0;
    float lp[5];
    for (int t0 = 1; t0 < hl; t0 += CH_) {
        const int te = (t0 + CH_ < hl) ? (t0 + CH_) : hl;
        const float* buf = chunkbuf[bsel];
        // first-step lp — the compiler's vmcnt drain lands here (chunk c's
        // DMA was issued one full chunk ago; c+1 not yet issued)
        {
            float lse_t = lseL[t0];
#pragma unroll
            for (int r = 0; r < 5; r++)
                lp[r] = (buf[1 + jr[r]] - lse_t) * LOG2E;
        }
        // issue chunk c+1 DMA into the other buffer (in flight during consume)
        if (t0 + CH_ < hl) {
            const char* gb = llbase + (size_t)(t0 + CH_) * 516 - 4;
            char* lb = (char*)&chunkbuf[bsel ^ 1][0];
#pragma unroll
            for (int i = 0; i < NLD_; i++)
                load_lds_16(gb + i * 1024 + lane * 16, lb + i * 1024 + lane * 16);
        }
        for (int t = t0; t < te; t++) {
            // depth-1 LDS prefetch of next step's lp (off the serial chain)
            float lpn[5];
            const bool more = (t + 1 < te);
            if (more) {
                float lse_n = lseL[t + 1];
                int fo = (t + 1 - t0) * 129 + 1;
#pragma unroll
                for (int r = 0; r < 5; r++)
                    lpn[r] = (buf[fo + jr[r]] - lse_n) * LOG2E;
            }
            // recurrence
            float p4 = __shfl_up(a[4], 1);   // s-1 for r=0
            float p3 = __shfl_up(a[3], 1);   // s-2 for r=0
            float na[5];
#pragma unroll
            for (int r = 0; r < 5; r++) {
                float a1 = a[r];
                float a2, a3;
                if (r == 0)      { a2 = p4;      a3 = p3; }
                else if (r == 1) { a2 = a[0];    a3 = p4; }
                else             { a2 = a[r-1];  a3 = a[r-2]; }
                if (r == 0 && lane == 0) { a2 = NEGF; a3 = NEGF; }
                a3 = al3[r] ? a3 : NEGF;
                float m = fmaxf(fmaxf(a1, a2), a3);
                float v = m + LOG2F(EXP2F(a1 - m) + EXP2F(a2 - m) + EXP2F(a3 - m));
                na[r] = val[r] ? (v + lp[r]) : NEGF;
            }
#pragma unroll
            for (int r = 0; r < 5; r++) a[r] = na[r];
            if (more) {
#pragma unroll
                for (int r = 0; r < 5; r++) lp[r] = lpn[r];
            }
        }
        bsel ^= 1;
    }

    // readout
#pragma unroll
    for (int r = 0; r < 5; r++) fin[sbase + r] = a[r];
    __syncthreads();
    if (lane == 0) {
        int yl = ys_lens[b];
        int i1 = 2 * yl;
        int i2 = (i1 > 0) ? i1 - 1 : 0;
        float x = fin[i1], y = fin[i2];
        float m = fmaxf(x, y);
        float llv = (m + LOG2F(EXP2F(x - m) + EXP2F(y - m))) * LN2;
        float loss = -llv;
        if (!isfinite(loss) || loss >= 1e29f) loss = 0.f;
        loss_b[b] = loss;
    }
}

// ---------------------------------------------------------------------------
// Kernel 6: final scalar: sum(loss_b) / sum(ys_lens)
// ---------------------------------------------------------------------------
__global__ void k_final(const float* __restrict__ loss_b,
                        const int* __restrict__ ys_lens,
                        float* __restrict__ out)
{
    int t = threadIdx.x;
    float v = (t < B_) ? loss_b[t] : 0.f;
    int   n = (t < B_) ? ys_lens[t] : 0;
    for (int off = 32; off > 0; off >>= 1) {
        v += __shfl_down(v, off, 64);
        n += __shfl_down(n, off, 64);
    }
    if (t == 0) out[0] = v / (float)n;
}

// ---------------------------------------------------------------------------
extern "C" void kernel_launch(void* const* d_in, const int* in_sizes, int n_in,
                              void* d_out, int out_size, void* d_ws, size_t ws_size,
                              hipStream_t stream)
{
    const float* hs      = (const float*)d_in[0];  // (B,T,D)
    const int*   hlens   = (const int*)  d_in[1];  // (B)
    const int*   ys      = (const int*)  d_in[2];  // (B,L)
    const int*   ys_lens = (const int*)  d_in[3];  // (B)
    const float* W       = (const float*)d_in[4];  // (D,V)
    const float* bias    = (const float*)d_in[5];  // (V)
    float* out = (float*)d_out;

    // Workspace layout (floats; all offsets 16B-aligned). Total ~40 MB.
    float* ws = (float*)d_ws;
    float* part_m = ws;                               // M*NT   = 655360
    float* part_s = part_m + (size_t)M_ * NT_;        // 655360
    float* lse    = part_s + (size_t)M_ * NT_;        // 16384
    float* Wg     = lse    + M_;                      // B*J*D  = 1056768
    float* bg     = Wg     + (size_t)B_ * J_ * D_;    // 2064
    float* llab   = bg     + (size_t)B_ * J_;         // 2113536
    float* loss_b = llab   + (size_t)B_ * T_ * J_;    // 16
    unsigned short* Ah = (unsigned short*)(loss_b + 16);   // M*D bf16 = 16.8MB
    unsigned short* Wt = Ah + (size_t)M_ * D_;             // VP*D bf16 = 5.2MB

    // 0) convert hs -> bf16; W -> bf16 transposed (N-major, padded to 5120)
    k_convert_hs<<<(M_ * D_) / (256 * 8), 256, 0, stream>>>(hs, Ah);
    k_transpose_w<<<dim3(VP_ / 32, D_ / 32), dim3(32, 8), 0, stream>>>(W, Wt);
    // 1) projection + fused partial LSE (the 84-GFLOP bulk) via bf16 MFMA
    k_gemm_lse_mfma<<<dim3(M_ / 128, NT_), 256, 0, stream>>>(Ah, Wt, bias, part_m, part_s);
    // 2) gather label columns of W
    k_gather_w<<<dim3(B_, J_), 128, 0, stream>>>(W, bias, ys, Wg, bg);
    // 3) label logits
    k_label_logits<<<dim3(B_, T_ / 16), 256, 0, stream>>>(hs, Wg, bg, llab);
    // 4) combine LSE partials
    k_lse_reduce<<<M_ / 256, 256, 0, stream>>>(part_m, part_s, lse);
    // 5) CTC forward recursion — one wave per batch, LDS-chunked ll staging
    k_ctc_alpha<<<B_, 64, 0, stream>>>(llab, lse, hlens, ys, ys_lens, loss_b);
    // 6) final scalar
    k_final<<<1, 64, 0, stream>>>(loss_b, ys_lens, out);
}